// Round 1
// baseline (542.556 us; speedup 1.0000x reference)
//
#include <hip/hip_runtime.h>
#include <stdint.h>

#define NEUR 1024
#define BM 64
#define THREADS 512

typedef short  s16x8  __attribute__((ext_vector_type(8)));
typedef __bf16 bf16x8 __attribute__((ext_vector_type(8)));
typedef float  f32x4  __attribute__((ext_vector_type(4)));

__device__ __forceinline__ unsigned short f2bf(float f){
  unsigned u = __builtin_bit_cast(unsigned, f);
  u += 0x7FFFu + ((u >> 16) & 1u);          // round-to-nearest-even
  return (unsigned short)(u >> 16);
}

__device__ __forceinline__ f32x4 mfma16(bf16x8 a, bf16x8 b, f32x4 c){
  return __builtin_amdgcn_mfma_f32_16x16x32_bf16(a, b, c, 0, 0, 0);
}

// Convert W2 (1024x1024 f32) -> bf16, and W1 (1024x10) -> [1024][32] bf16 zero-padded.
__global__ void prep_kernel(const float* __restrict__ W1, const float* __restrict__ W2,
                            unsigned short* __restrict__ w2bf, unsigned short* __restrict__ w1p){
  const int total = NEUR*NEUR + NEUR*32;
  for (int idx = blockIdx.x*blockDim.x + threadIdx.x; idx < total; idx += gridDim.x*blockDim.x){
    if (idx < NEUR*NEUR) w2bf[idx] = f2bf(W2[idx]);
    else {
      int j = idx - NEUR*NEUR; int n = j >> 5, i = j & 31;
      w1p[j] = (i < 10) ? f2bf(W1[n*10 + i]) : (unsigned short)0;
    }
  }
}

// Fused: features -> l1 -> h1(GEMM1,MFMA) -> h2(GEMM2,MFMA) -> logits(GEMM3,VALU) -> sigmoid
template<bool BFWS>
__global__ __launch_bounds__(THREADS, 2) void mlp_kernel(
    const float* __restrict__ x,
    const float* __restrict__ Wx, const float* __restrict__ bxp,
    const float* __restrict__ Wu, const float* __restrict__ bup,
    const float* __restrict__ W1, const float* __restrict__ b1,
    const float* __restrict__ W2f, const float* __restrict__ b2,
    const float* __restrict__ W3, const float* __restrict__ b3,
    const unsigned short* __restrict__ w2bf, const unsigned short* __restrict__ w1p,
    float* __restrict__ out)
{
  extern __shared__ char smem[];
  unsigned short* l1p  = (unsigned short*)smem;                 // [64][32] bf16 (4 KB)
  char* h1             = smem + 4096;                           // 64 rows * 2048 B, swizzled bf16 (128 KB)
  float* partial       = (float*)(smem + 4096 + BM*2048);       // [8][64][3] f32 (6 KB)

  const int tid  = threadIdx.x;
  const int lane = tid & 63;
  const int wid  = tid >> 6;
  const int r16  = lane & 15;    // fragment row/col lane index
  const int k16  = lane >> 4;    // fragment k-group
  const long rbase = (long)blockIdx.x * BM;

  // ---- 1. stage x tile (contiguous 64*25 floats), overlaying h1 region
  float* xs = (float*)h1;
  for (int i = tid; i < BM*25; i += THREADS) xs[i] = x[rbase*25 + i];
  __syncthreads();

  // ---- 2. l1 features (one row per thread, f32 exact)
  if (tid < BM){
    const float* xr = xs + tid*25;
    float l1v[10];
#pragma unroll
    for (int g = 0; g < 3; ++g){            // vx_, vy_, r_  (cols g + 3*i)
#pragma unroll
      for (int o = 0; o < 2; ++o){
        float s = bxp[o];
#pragma unroll
        for (int i = 0; i < 5; ++i) s += xr[g + 3*i] * Wx[o*5 + i];
        l1v[g*2 + o] = fmaxf(s, 0.f);
      }
    }
#pragma unroll
    for (int g = 0; g < 2; ++g){            // th_, st_ (cols 15+g+2*i)
#pragma unroll
      for (int o = 0; o < 2; ++o){
        float s = bup[o];
#pragma unroll
        for (int i = 0; i < 5; ++i) s += xr[15 + g + 2*i] * Wu[o*5 + i];
        l1v[6 + g*2 + o] = fmaxf(s, 0.f);
      }
    }
    unsigned short* dst = l1p + tid*32;
#pragma unroll
    for (int i = 0; i < 10; ++i) dst[i] = f2bf(l1v[i]);
#pragma unroll
    for (int i = 10; i < 32; ++i) dst[i] = 0;
  }
  __syncthreads();

  const int nb = wid * 128;   // this wave's 128-column slice of the 1024-wide hidden dim

  // ---- 3. GEMM1 (K=32 padded): h1[64][nb..nb+128) = relu(l1 @ W1^T + b1), store bf16 to LDS swizzled
  {
    bf16x8 a1[4];
#pragma unroll
    for (int mi = 0; mi < 4; ++mi){
      s16x8 raw = *reinterpret_cast<const s16x8*>(l1p + (mi*16 + r16)*32 + k16*8);
      a1[mi] = __builtin_bit_cast(bf16x8, raw);
    }
    f32x4 acc1[4][8];
#pragma unroll
    for (int mi = 0; mi < 4; ++mi)
#pragma unroll
      for (int ni = 0; ni < 8; ++ni) acc1[mi][ni] = f32x4{0.f,0.f,0.f,0.f};
#pragma unroll
    for (int ni = 0; ni < 8; ++ni){
      const int col = nb + ni*16 + r16;
      bf16x8 b;
      if constexpr (BFWS){
        s16x8 raw = *reinterpret_cast<const s16x8*>(w1p + col*32 + k16*8);
        b = __builtin_bit_cast(bf16x8, raw);
      } else {
        s16x8 raw;
#pragma unroll
        for (int j = 0; j < 8; ++j){
          const int kk = k16*8 + j;
          raw[j] = (kk < 10) ? (short)f2bf(W1[col*10 + kk]) : (short)0;
        }
        b = __builtin_bit_cast(bf16x8, raw);
      }
#pragma unroll
      for (int mi = 0; mi < 4; ++mi) acc1[mi][ni] = mfma16(a1[mi], b, acc1[mi][ni]);
    }
#pragma unroll
    for (int ni = 0; ni < 8; ++ni){
      const int col = nb + ni*16 + r16;
      const float b1v = b1[col];
#pragma unroll
      for (int mi = 0; mi < 4; ++mi)
#pragma unroll
        for (int r = 0; r < 4; ++r){
          const int row = mi*16 + k16*4 + r;
          const float v = fmaxf(acc1[mi][ni][r] + b1v, 0.f);
          *reinterpret_cast<unsigned short*>(h1 + row*2048 + ((col*2) ^ ((row & 7) << 4))) = f2bf(v);
        }
    }
  }
  __syncthreads();

  // ---- 4. GEMM2 main loop: h2 (64 x 128 per wave) over K=1024, no barriers
  f32x4 acc[4][8];
#pragma unroll
  for (int mi = 0; mi < 4; ++mi)
#pragma unroll
    for (int ni = 0; ni < 8; ++ni) acc[mi][ni] = f32x4{0.f,0.f,0.f,0.f};

#pragma unroll 4
  for (int ks = 0; ks < 32; ++ks){
    bf16x8 a[4];
#pragma unroll
    for (int mi = 0; mi < 4; ++mi){
      const int row = mi*16 + r16;
      s16x8 raw = *reinterpret_cast<const s16x8*>(
          h1 + row*2048 + ((ks*64 + k16*16) ^ ((row & 7) << 4)));
      a[mi] = __builtin_bit_cast(bf16x8, raw);
    }
#pragma unroll
    for (int ni = 0; ni < 8; ++ni){
      const int n = nb + ni*16 + r16;
      bf16x8 b;
      if constexpr (BFWS){
        s16x8 raw = *reinterpret_cast<const s16x8*>(w2bf + (size_t)n*NEUR + ks*32 + k16*8);
        b = __builtin_bit_cast(bf16x8, raw);
      } else {
        const float* wp = W2f + (size_t)n*NEUR + ks*32 + k16*8;
        s16x8 raw;
#pragma unroll
        for (int j = 0; j < 8; ++j) raw[j] = (short)f2bf(wp[j]);
        b = __builtin_bit_cast(bf16x8, raw);
      }
#pragma unroll
      for (int mi = 0; mi < 4; ++mi) acc[mi][ni] = mfma16(a[mi], b, acc[mi][ni]);
    }
  }

  // ---- 5. epilogue: +b2, relu, GEMM3 (f32), reduce, sigmoid
  float sum[4][4][3];
#pragma unroll
  for (int mi=0;mi<4;++mi)
#pragma unroll
    for (int r=0;r<4;++r)
#pragma unroll
      for (int j=0;j<3;++j) sum[mi][r][j] = 0.f;

#pragma unroll
  for (int ni = 0; ni < 8; ++ni){
    const int col = nb + ni*16 + r16;
    const float b2v = b2[col];
    float w3v[3];
#pragma unroll
    for (int j=0;j<3;++j) w3v[j] = W3[j*NEUR + col];
#pragma unroll
    for (int mi=0;mi<4;++mi)
#pragma unroll
      for (int r=0;r<4;++r){
        const float h = fmaxf(acc[mi][ni][r] + b2v, 0.f);
#pragma unroll
        for (int j=0;j<3;++j) sum[mi][r][j] += h * w3v[j];
      }
  }
  // reduce across the 16 column-lanes (xor over low 4 lane bits)
#pragma unroll
  for (int off = 1; off < 16; off <<= 1)
#pragma unroll
    for (int mi=0;mi<4;++mi)
#pragma unroll
      for (int r=0;r<4;++r)
#pragma unroll
        for (int j=0;j<3;++j) sum[mi][r][j] += __shfl_xor(sum[mi][r][j], off, 64);

  if (r16 == 0){
#pragma unroll
    for (int mi=0;mi<4;++mi)
#pragma unroll
      for (int r=0;r<4;++r){
        const int row = mi*16 + k16*4 + r;
#pragma unroll
        for (int j=0;j<3;++j) partial[(wid*BM + row)*3 + j] = sum[mi][r][j];
      }
  }
  __syncthreads();

  for (int t = tid; t < BM*3; t += THREADS){
    const int row = t / 3, j = t - (t/3)*3;
    float s = b3[j];
#pragma unroll
    for (int w = 0; w < 8; ++w) s += partial[(w*BM + row)*3 + j];
    out[(rbase + row)*3 + j] = 1.f / (1.f + __expf(-s));
  }
}

extern "C" void kernel_launch(void* const* d_in, const int* in_sizes, int n_in,
                              void* d_out, int out_size, void* d_ws, size_t ws_size,
                              hipStream_t stream){
  const float* x  = (const float*)d_in[0];
  const float* Wx = (const float*)d_in[1];
  const float* bx = (const float*)d_in[2];
  const float* Wu = (const float*)d_in[3];
  const float* bu = (const float*)d_in[4];
  const float* W1 = (const float*)d_in[5];
  const float* b1 = (const float*)d_in[6];
  const float* W2 = (const float*)d_in[7];
  const float* b2 = (const float*)d_in[8];
  const float* W3 = (const float*)d_in[9];
  const float* b3 = (const float*)d_in[10];
  float* out = (float*)d_out;

  const int batch   = in_sizes[0] / 25;
  const int nblocks = batch / BM;
  const size_t ws_need = (size_t)(NEUR*NEUR + NEUR*32) * sizeof(unsigned short);
  const int smem = 4096 + BM*2048 + 8*BM*3*4;   // 141312 B

  if (ws_size >= ws_need){
    unsigned short* w2bf = (unsigned short*)d_ws;
    unsigned short* w1p  = w2bf + NEUR*NEUR;
    prep_kernel<<<256, 256, 0, stream>>>(W1, W2, w2bf, w1p);
    hipFuncSetAttribute(reinterpret_cast<const void*>(mlp_kernel<true>),
                        hipFuncAttributeMaxDynamicSharedMemorySize, smem);
    mlp_kernel<true><<<nblocks, THREADS, smem, stream>>>(
        x, Wx, bx, Wu, bu, W1, b1, W2, b2, W3, b3, w2bf, w1p, out);
  } else {
    hipFuncSetAttribute(reinterpret_cast<const void*>(mlp_kernel<false>),
                        hipFuncAttributeMaxDynamicSharedMemorySize, smem);
    mlp_kernel<false><<<nblocks, THREADS, smem, stream>>>(
        x, Wx, bx, Wu, bu, W1, b1, W2, b2, W3, b3, nullptr, nullptr, out);
  }
}

// Round 2
// 450.368 us; speedup vs baseline: 1.2047x; 1.2047x over previous
//
#include <hip/hip_runtime.h>
#include <stdint.h>

#define NEUR 1024
#define BM 64
#define THREADS 1024

typedef short  s16x8  __attribute__((ext_vector_type(8)));
typedef __bf16 bf16x8 __attribute__((ext_vector_type(8)));
typedef float  f32x16 __attribute__((ext_vector_type(16)));

__device__ __forceinline__ unsigned short f2bf(float f){
  unsigned u = __builtin_bit_cast(unsigned, f);
  u += 0x7FFFu + ((u >> 16) & 1u);          // round-to-nearest-even
  return (unsigned short)(u >> 16);
}
__device__ __forceinline__ float bf2f(unsigned short h){
  unsigned u = ((unsigned)h) << 16;
  return __builtin_bit_cast(float, u);
}
__device__ __forceinline__ f32x16 mfma32(bf16x8 a, bf16x8 b, f32x16 c){
  return __builtin_amdgcn_mfma_f32_32x32x16_bf16(a, b, c, 0, 0, 0);
}

// Pre-swizzle weights into MFMA-fragment order so GEMM loads are coalesced.
// w2opt[((nt*64 + ks)*64 + l)*8 + j] = bf16(W2[nt*32 + (l&31)][ks*16 + (l>>5)*8 + j])
// w1opt[((nt*2  + ks)*64 + l)*8 + j] = bf16(W1 padded to K=32, same fragment map)
__global__ void prep_kernel(const float* __restrict__ W1, const float* __restrict__ W2,
                            unsigned short* __restrict__ w2opt, unsigned short* __restrict__ w1opt){
  const int nchunks = NEUR * 128;            // 8-float chunks of W2 (read-coalesced)
  const int total = nchunks + 4096;          // + w1opt lane-blocks
  for (int i = blockIdx.x*blockDim.x + threadIdx.x; i < total; i += gridDim.x*blockDim.x){
    if (i < nchunks){
      const int col = i >> 7, c8 = i & 127;
      const float* src = W2 + (size_t)col*NEUR + c8*8;
      const int ks = c8 >> 1, lh = c8 & 1, l = lh*32 + (col & 31), nt = col >> 5;
      unsigned short* dst = w2opt + (((size_t)(nt*64 + ks)*64 + l) * 8);
#pragma unroll
      for (int j = 0; j < 8; ++j) dst[j] = f2bf(src[j]);
    } else {
      const int o = i - nchunks;             // ((nt*2+ks)*64 + l)
      const int nt = o >> 7, ks = (o >> 6) & 1, l = o & 63;
      const int col = nt*32 + (l & 31);
      unsigned short* dst = w1opt + (size_t)o * 8;
#pragma unroll
      for (int j = 0; j < 8; ++j){
        const int k = ks*16 + (l >> 5)*8 + j;
        dst[j] = (k < 10) ? f2bf(W1[col*10 + k]) : (unsigned short)0;
      }
    }
  }
}

template<bool BFWS>
__global__ __launch_bounds__(THREADS, 4) void mlp_kernel(
    const float* __restrict__ x,
    const float* __restrict__ Wx, const float* __restrict__ bxp,
    const float* __restrict__ Wu, const float* __restrict__ bup,
    const float* __restrict__ W1, const float* __restrict__ b1,
    const float* __restrict__ W2f, const float* __restrict__ b2,
    const float* __restrict__ W3, const float* __restrict__ b3,
    const unsigned short* __restrict__ w2opt, const unsigned short* __restrict__ w1opt,
    float* __restrict__ out)
{
  extern __shared__ char smem[];
  unsigned short* l1p = (unsigned short*)smem;   // [64][40] bf16 (5120 B, padded stride)
  char* h1            = smem + 5120;             // 64 rows x 2048 B, XOR-swizzled bf16

  const int tid = threadIdx.x;
  const int l   = tid & 63;
  const int wid = tid >> 6;                      // 16 waves
  const int l31 = l & 31;
  const int lh  = l >> 5;
  const long rbase = (long)blockIdx.x * BM;

  // ---- 1. stage x tile (64*25 f32), overlaying h1 region
  float* xs = (float*)h1;
  for (int i = tid; i < BM*25; i += THREADS) xs[i] = x[rbase*25 + i];
  __syncthreads();

  // ---- 2. l1 features (f32 exact), bf16-pad to K=32 in l1p
  if (tid < BM){
    const float* xr = xs + tid*25;
    float l1v[10];
#pragma unroll
    for (int g = 0; g < 3; ++g)
#pragma unroll
      for (int o = 0; o < 2; ++o){
        float s = bxp[o];
#pragma unroll
        for (int i = 0; i < 5; ++i) s += xr[g + 3*i] * Wx[o*5 + i];
        l1v[g*2 + o] = fmaxf(s, 0.f);
      }
#pragma unroll
    for (int g = 0; g < 2; ++g)
#pragma unroll
      for (int o = 0; o < 2; ++o){
        float s = bup[o];
#pragma unroll
        for (int i = 0; i < 5; ++i) s += xr[15 + g + 2*i] * Wu[o*5 + i];
        l1v[6 + g*2 + o] = fmaxf(s, 0.f);
      }
    unsigned short* dst = l1p + tid*40;
#pragma unroll
    for (int i = 0; i < 10; ++i) dst[i] = f2bf(l1v[i]);
#pragma unroll
    for (int i = 10; i < 32; ++i) dst[i] = 0;
  }
  __syncthreads();

  const int swz = (l31 & 7) << 4;                // row-dependent LDS XOR swizzle

  // ---- 3. GEMM1: h1[64][wid*64 .. +64) = relu(l1 @ W1^T + b1)  (32x32x16 MFMA)
  {
    f32x16 acc1[2][2];
#pragma unroll
    for (int mt = 0; mt < 2; ++mt)
#pragma unroll
      for (int nt = 0; nt < 2; ++nt)
#pragma unroll
        for (int r = 0; r < 16; ++r) acc1[mt][nt][r] = 0.f;

#pragma unroll
    for (int ks = 0; ks < 2; ++ks){
      bf16x8 aF[2], bF[2];
#pragma unroll
      for (int mt = 0; mt < 2; ++mt){
        s16x8 raw = *reinterpret_cast<const s16x8*>(smem + (mt*32 + l31)*80 + ks*32 + lh*16);
        aF[mt] = __builtin_bit_cast(bf16x8, raw);
      }
#pragma unroll
      for (int nt = 0; nt < 2; ++nt){
        if constexpr (BFWS){
          s16x8 raw = *reinterpret_cast<const s16x8*>(
              w1opt + (((size_t)((wid*2 + nt)*2 + ks)*64 + l) * 8));
          bF[nt] = __builtin_bit_cast(bf16x8, raw);
        } else {
          const int col = wid*64 + nt*32 + l31;
          s16x8 raw;
#pragma unroll
          for (int j = 0; j < 8; ++j){
            const int k = ks*16 + lh*8 + j;
            raw[j] = (k < 10) ? (short)f2bf(W1[col*10 + k]) : (short)0;
          }
          bF[nt] = __builtin_bit_cast(bf16x8, raw);
        }
      }
#pragma unroll
      for (int mt = 0; mt < 2; ++mt)
#pragma unroll
        for (int nt = 0; nt < 2; ++nt) acc1[mt][nt] = mfma32(aF[mt], bF[nt], acc1[mt][nt]);
    }
#pragma unroll
    for (int nt = 0; nt < 2; ++nt){
      const int col = wid*64 + nt*32 + l31;
      const float b1v = b1[col];
#pragma unroll
      for (int mt = 0; mt < 2; ++mt)
#pragma unroll
        for (int r = 0; r < 16; ++r){
          const int row = mt*32 + (r & 3) + 8*(r >> 2) + 4*lh;
          const float v = fmaxf(acc1[mt][nt][r] + b1v, 0.f);
          *reinterpret_cast<unsigned short*>(h1 + row*2048 + ((col*2) ^ ((row & 7) << 4))) = f2bf(v);
        }
    }
  }
  __syncthreads();

  // ---- 4. GEMM2: per wave 64 rows x 64 cols, K=1024, 1-deep register pipeline
  f32x16 acc[2][2];
#pragma unroll
  for (int mt = 0; mt < 2; ++mt)
#pragma unroll
    for (int nt = 0; nt < 2; ++nt)
#pragma unroll
      for (int r = 0; r < 16; ++r) acc[mt][nt][r] = 0.f;

  const unsigned short* w2b0 = w2opt + ((size_t)(wid*2 + 0)*64*64 + l) * 8;
  const unsigned short* w2b1 = w2opt + ((size_t)(wid*2 + 1)*64*64 + l) * 8;

  auto loadA = [&](int ks, bf16x8& A0, bf16x8& A1){
    const int cb = (ks*32 + lh*16) ^ swz;
    s16x8 r0 = *reinterpret_cast<const s16x8*>(h1 + l31*2048 + cb);
    s16x8 r1 = *reinterpret_cast<const s16x8*>(h1 + (32 + l31)*2048 + cb);
    A0 = __builtin_bit_cast(bf16x8, r0);
    A1 = __builtin_bit_cast(bf16x8, r1);
  };
  auto loadB = [&](int ks, bf16x8& B0, bf16x8& B1){
    if constexpr (BFWS){
      s16x8 r0 = *reinterpret_cast<const s16x8*>(w2b0 + ks*512);
      s16x8 r1 = *reinterpret_cast<const s16x8*>(w2b1 + ks*512);
      B0 = __builtin_bit_cast(bf16x8, r0);
      B1 = __builtin_bit_cast(bf16x8, r1);
    } else {
      const int col0 = wid*64 + l31, col1 = col0 + 32;
      const float* p0 = W2f + (size_t)col0*NEUR + ks*16 + lh*8;
      const float* p1 = W2f + (size_t)col1*NEUR + ks*16 + lh*8;
      s16x8 r0, r1;
#pragma unroll
      for (int j = 0; j < 8; ++j){ r0[j] = (short)f2bf(p0[j]); r1[j] = (short)f2bf(p1[j]); }
      B0 = __builtin_bit_cast(bf16x8, r0);
      B1 = __builtin_bit_cast(bf16x8, r1);
    }
  };

  bf16x8 A0a, A1a, B0a, B1a, A0b, A1b, B0b, B1b;
  loadA(0, A0a, A1a); loadB(0, B0a, B1a);
  for (int ks = 0; ks < 64; ks += 2){
    loadA(ks + 1, A0b, A1b); loadB(ks + 1, B0b, B1b);
    acc[0][0] = mfma32(A0a, B0a, acc[0][0]);
    acc[1][0] = mfma32(A1a, B0a, acc[1][0]);
    acc[0][1] = mfma32(A0a, B1a, acc[0][1]);
    acc[1][1] = mfma32(A1a, B1a, acc[1][1]);
    if (ks + 2 < 64){ loadA(ks + 2, A0a, A1a); loadB(ks + 2, B0a, B1a); }
    acc[0][0] = mfma32(A0b, B0b, acc[0][0]);
    acc[1][0] = mfma32(A1b, B0b, acc[1][0]);
    acc[0][1] = mfma32(A0b, B1b, acc[0][1]);
    acc[1][1] = mfma32(A1b, B1b, acc[1][1]);
  }
  __syncthreads();   // everyone done reading h1

  // ---- 5. h2 = relu(acc + b2) -> back into h1 (bf16, swizzled)
#pragma unroll
  for (int nt = 0; nt < 2; ++nt){
    const int col = wid*64 + nt*32 + l31;
    const float b2v = b2[col];
#pragma unroll
    for (int mt = 0; mt < 2; ++mt)
#pragma unroll
      for (int r = 0; r < 16; ++r){
        const int row = mt*32 + (r & 3) + 8*(r >> 2) + 4*lh;
        const float v = fmaxf(acc[mt][nt][r] + b2v, 0.f);
        *reinterpret_cast<unsigned short*>(h1 + row*2048 + ((col*2) ^ ((row & 7) << 4))) = f2bf(v);
      }
  }
  __syncthreads();

  // ---- 6. GEMM3 (f32 VALU): wave wid owns rows wid*4 .. wid*4+3
  float s[4][3];
#pragma unroll
  for (int rr = 0; rr < 4; ++rr)
#pragma unroll
    for (int j = 0; j < 3; ++j) s[rr][j] = 0.f;

#pragma unroll
  for (int h = 0; h < 2; ++h){
    const int k0 = h*512 + l*8;
    float w3v[3][8];
#pragma unroll
    for (int j = 0; j < 3; ++j)
#pragma unroll
      for (int i = 0; i < 8; ++i) w3v[j][i] = W3[j*NEUR + k0 + i];
#pragma unroll
    for (int rr = 0; rr < 4; ++rr){
      const int row = wid*4 + rr;
      s16x8 raw = *reinterpret_cast<const s16x8*>(
          h1 + row*2048 + ((h*1024 + l*16) ^ ((row & 7) << 4)));
#pragma unroll
      for (int i = 0; i < 8; ++i){
        const float hv = bf2f((unsigned short)raw[i]);
        s[rr][0] += hv * w3v[0][i];
        s[rr][1] += hv * w3v[1][i];
        s[rr][2] += hv * w3v[2][i];
      }
    }
  }
#pragma unroll
  for (int off = 1; off < 64; off <<= 1)
#pragma unroll
    for (int rr = 0; rr < 4; ++rr)
#pragma unroll
      for (int j = 0; j < 3; ++j) s[rr][j] += __shfl_xor(s[rr][j], off, 64);

  if (l == 0){
#pragma unroll
    for (int rr = 0; rr < 4; ++rr){
      const int row = wid*4 + rr;
#pragma unroll
      for (int j = 0; j < 3; ++j){
        const float v = s[rr][j] + b3[j];
        out[(rbase + row)*3 + j] = 1.f / (1.f + __expf(-v));
      }
    }
  }
}

extern "C" void kernel_launch(void* const* d_in, const int* in_sizes, int n_in,
                              void* d_out, int out_size, void* d_ws, size_t ws_size,
                              hipStream_t stream){
  const float* x  = (const float*)d_in[0];
  const float* Wx = (const float*)d_in[1];
  const float* bx = (const float*)d_in[2];
  const float* Wu = (const float*)d_in[3];
  const float* bu = (const float*)d_in[4];
  const float* W1 = (const float*)d_in[5];
  const float* b1 = (const float*)d_in[6];
  const float* W2 = (const float*)d_in[7];
  const float* b2 = (const float*)d_in[8];
  const float* W3 = (const float*)d_in[9];
  const float* b3 = (const float*)d_in[10];
  float* out = (float*)d_out;

  const int batch   = in_sizes[0] / 25;
  const int nblocks = batch / BM;
  const size_t ws_need = (size_t)(32*64*64*8 + 4096*8) * sizeof(unsigned short); // ~2.1 MB
  const int smem = 5120 + BM*2048;   // 136192 B

  if (ws_size >= ws_need){
    unsigned short* w2opt = (unsigned short*)d_ws;
    unsigned short* w1opt = w2opt + (size_t)32*64*64*8;
    prep_kernel<<<512, 256, 0, stream>>>(W1, W2, w2opt, w1opt);
    hipFuncSetAttribute(reinterpret_cast<const void*>(mlp_kernel<true>),
                        hipFuncAttributeMaxDynamicSharedMemorySize, smem);
    mlp_kernel<true><<<nblocks, THREADS, smem, stream>>>(
        x, Wx, bx, Wu, bu, W1, b1, W2, b2, W3, b3, w2opt, w1opt, out);
  } else {
    hipFuncSetAttribute(reinterpret_cast<const void*>(mlp_kernel<false>),
                        hipFuncAttributeMaxDynamicSharedMemorySize, smem);
    mlp_kernel<false><<<nblocks, THREADS, smem, stream>>>(
        x, Wx, bx, Wu, bu, W1, b1, W2, b2, W3, b3, nullptr, nullptr, out);
  }
}